// Round 2
// baseline (257.662 us; speedup 1.0000x reference)
//
#include <hip/hip_runtime.h>

// Problem constants (from reference)
#define NV      163842      // vertices
#define CIN     64
#define KN      7
#define NKMAX   (NV * KN)   // 1,146,894 valid neigh entries
#define KDIM    448         // 7*64
#define KSTEPS  14          // 448 / 32
#define VPC     16          // vertices per chunk
#define ROWS    32          // M-rows per chunk (VPC * 2 batches)
#define ASTRIDE 456         // LDS row stride in bf16 units (448 + 8 pad; 912B, 16B-aligned)
#define ABUF    (ROWS * ASTRIDE)   // shorts per A buffer (14592; 29184 B)

typedef short  short8 __attribute__((ext_vector_type(8)));
typedef float  f32x4  __attribute__((ext_vector_type(4)));
typedef float  f32x2  __attribute__((ext_vector_type(2)));

static __device__ __forceinline__ unsigned int pack_bf16(float a, float b) {
#if __has_builtin(__builtin_amdgcn_cvt_pk_bf16_f32)
    typedef __bf16 bf16x2 __attribute__((ext_vector_type(2)));
    union { bf16x2 v; unsigned int u; } cv;
    cv.v = __builtin_amdgcn_cvt_pk_bf16_f32(a, b);
    return cv.u;
#else
    unsigned int ua = __float_as_uint(a);
    unsigned int ub = __float_as_uint(b);
    ua = (ua + 0x7FFFu + ((ua >> 16) & 1u)) >> 16;
    ub = (ub + 0x7FFFu + ((ub >> 16) & 1u)) & 0xFFFF0000u;
    return ua | ub;
#endif
}

// LDS-only barrier: drains lgkmcnt but leaves the vmcnt (global prefetch) queue
// alive across s_barrier. __syncthreads() would emit s_waitcnt vmcnt(0) and
// destroy the cross-chunk pipeline.
static __device__ __forceinline__ void bar_lgkm() {
    asm volatile("s_waitcnt lgkmcnt(0)\n\ts_barrier" ::: "memory");
}

// ---- pre-pass: x [N][C][B] fp32 -> x_t [B][N][C] bf16 (de-interleave + cast) ----
__global__ __launch_bounds__(256)
void xcast(const float* __restrict__ x, unsigned int* __restrict__ xt, int nf4)
{
    const int f = blockIdx.x * 256 + threadIdx.x;   // float4 index over x
    if (f >= nf4) return;                           // nf4 = NV*32
    const f32x4 g = __builtin_nontemporal_load(&((const f32x4*)x)[f]);
    const int v = f >> 5;
    const int r = f & 31;                           // u32 slot; c0 = 2r
    xt[v * 32 + r]           = pack_bf16(g[0], g[2]); // batch 0: c0, c0+1
    xt[NV * 32 + v * 32 + r] = pack_bf16(g[1], g[3]); // batch 1
}

// ---- main v3: 256 threads, A double-buffered (1 barrier/chunk), wave-private
//      C staging (no barrier), 16x32 wave tiles -> 256B-granule-clean nt stores.
//      v2 lesson: stores must cover full 256B HBM granules per instruction,
//      else RMW doubles WRITE_SIZE and adds FETCH traffic. ----
__global__ __launch_bounds__(256, 2)
void onering_mfma_bf16_v3(const unsigned short* __restrict__ xt,
                          const int* __restrict__ neigh,
                          const float* __restrict__ W,
                          const float* __restrict__ bias,
                          float* __restrict__ out,
                          int nchunks)
{
    __shared__ __align__(16) unsigned short A_lds[2 * ABUF];  // 58368 B double buffer
    __shared__ __align__(16) float          C_lds[4 * 512];   // 8192 B, 2KB/wave private

    const int tid  = threadIdx.x;
    const int lane = tid & 63;
    const int w    = tid >> 6;       // wave 0..3
    const int wc   = w & 1;          // col half: o in [wc*32, wc*32+32)
    const int wr   = w >> 1;         // row half: rows [wr*16, wr*16+16)
    const int ncol = lane & 15;
    const int kgrp = lane >> 4;
    const int G    = gridDim.x;

    // ---- persistent B fragments: TWO 16-col tiles per wave (112 VGPR).
    //      Same A fragment feeds both MFMAs -> fragment ds_reads halve vs v1. ----
    short8 bfrag0[KSTEPS], bfrag1[KSTEPS];
    const int o0 = wc * 32 + ncol;
    const int o1 = o0 + 16;
    {
#pragma unroll
        for (int s = 0; s < KSTEPS; ++s) {
            const int kb = s * 32 + kgrp * 8;
            const float4* wp0 = (const float4*)(W + o0 * KDIM + kb);
            const float4* wp1 = (const float4*)(W + o1 * KDIM + kb);
            float4 a0 = wp0[0], a1 = wp0[1];
            float4 b0 = wp1[0], b1 = wp1[1];
            union { short8 v; unsigned int u[4]; } pk;
            pk.u[0] = pack_bf16(a0.x, a0.y);
            pk.u[1] = pack_bf16(a0.z, a0.w);
            pk.u[2] = pack_bf16(a1.x, a1.y);
            pk.u[3] = pack_bf16(a1.z, a1.w);
            bfrag0[s] = pk.v;
            pk.u[0] = pack_bf16(b0.x, b0.y);
            pk.u[1] = pack_bf16(b0.z, b0.w);
            pk.u[2] = pack_bf16(b1.x, b1.y);
            pk.u[3] = pack_bf16(b1.z, b1.w);
            bfrag1[s] = pk.v;
        }
    }
    const float bias0 = bias[o0];
    const float bias1 = bias[o1];

    // ---- staging plan: 224 segments (row 0..31, k 0..6), 8 lanes x 16B each ----
    const int l8 = tid & 7;
    int nidx[7];      // lv*7 + k      (neigh offset within chunk)
    int lbyte[7];     // byte addr within one A buffer
    int soff[7];      // short offset within xt: bb*NV*64 + l8*8
#pragma unroll
    for (int i = 0; i < 7; ++i) {
        const int seg = (tid >> 3) + 32 * i;
        const int row = seg / 7;
        const int k   = seg - row * 7;
        const int lv  = row >> 1, bb = row & 1;
        nidx[i]  = lv * KN + k;
        lbyte[i] = row * (ASTRIDE * 2) + k * 128 + l8 * 16;
        soff[i]  = bb * (NV * 64) + l8 * 8;
    }

    const int ch0 = blockIdx.x;
    int    I[7];      // neigh indices  (pipeline stage: ch+2G)
    short8 R[7];      // gathered rows  (pipeline stage: ch+G)

    // ---- prologue: stage ch0 into buffer 0; fill 3-stage pipeline ----
#pragma unroll
    for (int i = 0; i < 7; ++i) {
        int gi = ch0 * (VPC * KN) + nidx[i];
        I[i] = __builtin_nontemporal_load(&neigh[gi < NKMAX ? gi : 0]);
    }
#pragma unroll
    for (int i = 0; i < 7; ++i)
        R[i] = *(const short8*)(xt + soff[i] + I[i] * 64);
#pragma unroll
    for (int i = 0; i < 7; ++i)
        *(short8*)((char*)A_lds + lbyte[i]) = R[i];
#pragma unroll
    for (int i = 0; i < 7; ++i) {
        int gi = (ch0 + G) * (VPC * KN) + nidx[i];
        I[i] = __builtin_nontemporal_load(&neigh[gi < NKMAX ? gi : 0]);
    }
#pragma unroll
    for (int i = 0; i < 7; ++i)
        R[i] = *(const short8*)(xt + soff[i] + I[i] * 64);
#pragma unroll
    for (int i = 0; i < 7; ++i) {
        int gi = (ch0 + 2 * G) * (VPC * KN) + nidx[i];
        I[i] = __builtin_nontemporal_load(&neigh[gi < NKMAX ? gi : 0]);
    }
    bar_lgkm();   // buf0 = ch0 published; R = ch0+G in regs; I = ch0+2G in flight

    int rbuf = 0;
    float* const Cw = C_lds + w * 512;      // wave-private 2KB tile
    const int vt0 = wr * 8;                 // first local vertex of this wave's tile
    const int cb  = wc * 64;                // float col base within out row (256B)

    for (int ch = ch0; ch < nchunks; ch += G) {
        const int vb = ch * VPC;

        // ---- 1. compute chunk ch from FRONT buffer: 14 ds_read_b128, 28 MFMA ----
        const unsigned short* Ap = A_lds + rbuf * ABUF + (wr * 16 + ncol) * ASTRIDE;
        f32x4 acc0 = {0.f, 0.f, 0.f, 0.f};
        f32x4 acc1 = {0.f, 0.f, 0.f, 0.f};
#pragma unroll
        for (int s = 0; s < KSTEPS; ++s) {
            const short8 a = *(const short8*)&Ap[s * 32 + kgrp * 8];
            acc0 = __builtin_amdgcn_mfma_f32_16x16x32_bf16(a, bfrag0[s], acc0, 0, 0, 0);
            acc1 = __builtin_amdgcn_mfma_f32_16x16x32_bf16(a, bfrag1[s], acc1, 0, 0, 0);
        }

        // ---- 2. stage chunk ch+G into BACK buffer (gathers issued last iter) ----
        char* wbase = (char*)A_lds + (rbuf ^ 1) * (ABUF * 2);
#pragma unroll
        for (int i = 0; i < 7; ++i)
            *(short8*)(wbase + lbyte[i]) = R[i];
        // ---- 3. gather ch+2G ----
#pragma unroll
        for (int i = 0; i < 7; ++i)
            R[i] = *(const short8*)(xt + soff[i] + I[i] * 64);
        // ---- 4. idx prefetch ch+3G ----
#pragma unroll
        for (int i = 0; i < 7; ++i) {
            int gi = (ch + 3 * G) * (VPC * KN) + nidx[i];
            I[i] = __builtin_nontemporal_load(&neigh[gi < NKMAX ? gi : 0]);
        }

        // ---- 5. wave-private epilogue: no barrier needed.
        //      acc layout: reg j of acc{0,1} -> row r = kgrp*4+j (r = 2*lvv + batch),
        //      col o0/o1. Write pairs (j, j+1) = batches 0,1 of vertex lvv. ----
#pragma unroll
        for (int p = 0; p < 2; ++p) {
            const int lvv = kgrp * 2 + p;
            f32x2 v0 = { acc0[2 * p] + bias0, acc0[2 * p + 1] + bias0 };
            f32x2 v1 = { acc1[2 * p] + bias1, acc1[2 * p + 1] + bias1 };
            *(f32x2*)&Cw[lvv * 64 + ncol * 2]        = v0;   // cols o0: conflict-free b64
            *(f32x2*)&Cw[lvv * 64 + (16 + ncol) * 2] = v1;   // cols o1
        }
        // read back linearly; 1KB/instr = 4 full 256B granules per store
#pragma unroll
        for (int i = 0; i < 2; ++i) {
            const int fo  = (i * 64 + lane) * 4;   // float offset in 512-float tile
            const int lvv = fo >> 6;
            const int rem = fo & 63;
            const int n   = vb + vt0 + lvv;
            if (n < NV) {
                f32x4 val = *(const f32x4*)&Cw[fo];
                __builtin_nontemporal_store(val, (f32x4*)(out + (size_t)n * 128 + cb + rem));
            }
        }

        bar_lgkm();   // publish back buffer; all front-buffer reads drained
        rbuf ^= 1;
    }
}

// ---- fallback (ws too small): fp32-gather kernel (unchanged) ----
__global__ __launch_bounds__(256, 4)
void onering_mfma_f32(const float* __restrict__ x,
                      const int* __restrict__ neigh,
                      const float* __restrict__ W,
                      const float* __restrict__ bias,
                      float* __restrict__ out,
                      int nchunks)
{
    __shared__ unsigned short A_lds[ROWS * ASTRIDE];
    const int tid  = threadIdx.x;
    const int lane = tid & 63;
    const int w    = tid >> 6;
    const int ncol = lane & 15;
    const int kgrp = lane >> 4;

    short8 bfrag[KSTEPS];
    {
        const int o = w * 16 + ncol;
#pragma unroll
        for (int s = 0; s < KSTEPS; ++s) {
            const int kb = s * 32 + kgrp * 8;
            const float4* wp = (const float4*)(W + o * KDIM + kb);
            float4 w0 = wp[0];
            float4 w1 = wp[1];
            union { short8 v; unsigned int u[4]; } pk;
            pk.u[0] = pack_bf16(w0.x, w0.y);
            pk.u[1] = pack_bf16(w0.z, w0.w);
            pk.u[2] = pack_bf16(w1.x, w1.y);
            pk.u[3] = pack_bf16(w1.z, w1.w);
            bfrag[s] = pk.v;
        }
    }
    const float biasv = bias[w * 16 + ncol];
    const int off4  = tid & 31;
    const int sbase = tid >> 5;

    for (int ch = blockIdx.x; ch < nchunks; ch += gridDim.x) {
        const int vb = ch * VPC;
        __syncthreads();
#pragma unroll
        for (int i = 0; i < 14; ++i) {
            const int s  = sbase + 8 * i;
            const int lv = s / 7;
            const int k  = s - lv * 7;
            const int n  = vb + lv;
            int vi = 0;
            if (n < NV) vi = neigh[n * KN + k];
            const float4 g = ((const float4*)x)[vi * 32 + off4];
            const int base = k * 64 + 2 * off4;
            ((unsigned int*)A_lds)[((lv * 2)     * ASTRIDE + base) >> 1] = pack_bf16(g.x, g.z);
            ((unsigned int*)A_lds)[((lv * 2 + 1) * ASTRIDE + base) >> 1] = pack_bf16(g.y, g.w);
        }
        __syncthreads();
        f32x4 acc0 = {0.f, 0.f, 0.f, 0.f};
        f32x4 acc1 = {0.f, 0.f, 0.f, 0.f};
#pragma unroll
        for (int s = 0; s < KSTEPS; ++s) {
            const int kb = s * 32 + kgrp * 8;
            const short8 a0 = *(const short8*)&A_lds[ncol * ASTRIDE + kb];
            const short8 a1 = *(const short8*)&A_lds[(16 + ncol) * ASTRIDE + kb];
            acc0 = __builtin_amdgcn_mfma_f32_16x16x32_bf16(a0, bfrag[s], acc0, 0, 0, 0);
            acc1 = __builtin_amdgcn_mfma_f32_16x16x32_bf16(a1, bfrag[s], acc1, 0, 0, 0);
        }
        const int o = w * 16 + ncol;
#pragma unroll
        for (int j = 0; j < 4; ++j) {
            const int r = kgrp * 4 + j;
            {
                const int lv = r >> 1, bb = r & 1, n = vb + lv;
                if (n < NV) out[n * 128 + o * 2 + bb] = acc0[j] + biasv;
            }
            {
                const int m = 16 + r;
                const int lv = m >> 1, bb = m & 1, n = vb + lv;
                if (n < NV) out[n * 128 + o * 2 + bb] = acc1[j] + biasv;
            }
        }
    }
}

extern "C" void kernel_launch(void* const* d_in, const int* in_sizes, int n_in,
                              void* d_out, int out_size, void* d_ws, size_t ws_size,
                              hipStream_t stream) {
    const float* x     = (const float*)d_in[0];
    const int*   neigh = (const int*)d_in[1];   // int64 in ref -> int32 from harness
    const float* W     = (const float*)d_in[2];
    const float* bias  = (const float*)d_in[3];
    float*       out   = (float*)d_out;

    const int nchunks = (NV + VPC - 1) / VPC;   // 10241
    const size_t need = (size_t)2 * NV * 64 * sizeof(unsigned short);  // 41.9 MB

    if (ws_size >= need) {
        unsigned short* xt = (unsigned short*)d_ws;
        const int nf4 = NV * 32;
        xcast<<<dim3((nf4 + 255) / 256), dim3(256), 0, stream>>>(x, (unsigned int*)xt, nf4);
        onering_mfma_bf16_v3<<<dim3(2048), dim3(256), 0, stream>>>(xt, neigh, W, bias, out, nchunks);
    } else {
        onering_mfma_f32<<<dim3(2560), dim3(256), 0, stream>>>(x, neigh, W, bias, out, nchunks);
    }
}

// Round 3
// 209.691 us; speedup vs baseline: 1.2288x; 1.2288x over previous
//
#include <hip/hip_runtime.h>

// Problem constants (from reference)
#define NV      163842      // vertices
#define CIN     64
#define KN      7
#define NKMAX   (NV * KN)   // 1,146,894 valid neigh entries
#define KDIM    448         // 7*64
#define KSTEPS  14          // 448 / 32
#define VPC     16          // vertices per chunk
#define ROWS    32          // M-rows per chunk (VPC * 2 batches)
#define ASTRIDE 456         // LDS row stride in bf16 units (448 + 8 pad; 912B, 16B-aligned)

typedef short  short8 __attribute__((ext_vector_type(8)));
typedef float  f32x4  __attribute__((ext_vector_type(4)));

static __device__ __forceinline__ unsigned int pack_bf16(float a, float b) {
#if __has_builtin(__builtin_amdgcn_cvt_pk_bf16_f32)
    typedef __bf16 bf16x2 __attribute__((ext_vector_type(2)));
    union { bf16x2 v; unsigned int u; } cv;
    cv.v = __builtin_amdgcn_cvt_pk_bf16_f32(a, b);
    return cv.u;
#else
    unsigned int ua = __float_as_uint(a);
    unsigned int ub = __float_as_uint(b);
    ua = (ua + 0x7FFFu + ((ua >> 16) & 1u)) >> 16;
    ub = (ub + 0x7FFFu + ((ub >> 16) & 1u)) & 0xFFFF0000u;
    return ua | ub;
#endif
}

// LDS-only barrier: drains lgkmcnt but leaves the vmcnt (global prefetch) queue
// alive across s_barrier. __syncthreads() would emit s_waitcnt vmcnt(0) and
// destroy the cross-chunk pipeline.
static __device__ __forceinline__ void bar_lgkm() {
    asm volatile("s_waitcnt lgkmcnt(0)\n\ts_barrier" ::: "memory");
}

// ---- pre-pass: x [N][C][B] fp32 -> xt [N][B][C] bf16 (256B per vertex).
//      v4: both batches ADJACENT so each neighbor gather is one contiguous
//      256B burst instead of two random 128B lines 21MB apart. ----
__global__ __launch_bounds__(256)
void xcast(const float* __restrict__ x, unsigned int* __restrict__ xt, int nf4)
{
    const int f = blockIdx.x * 256 + threadIdx.x;   // float4 index over x
    if (f >= nf4) return;                           // nf4 = NV*32
    const f32x4 g = __builtin_nontemporal_load(&((const f32x4*)x)[f]);
    const int v = f >> 5;
    const int r = f & 31;                           // u32 slot; c0 = 2r
    xt[v * 64 + r]      = pack_bf16(g[0], g[2]);    // batch 0: c0, c0+1
    xt[v * 64 + 32 + r] = pack_bf16(g[1], g[3]);    // batch 1
}

// ---- main v4: v1 structure (3-stage pipeline, C_lds epilogue, clean 4KB
//      stores) + 256B-burst gathers + persistent grid (4 blocks/CU). ----
__global__ __launch_bounds__(256, 3)
void onering_mfma_bf16_v4(const unsigned short* __restrict__ xt,
                          const int* __restrict__ neigh,
                          const float* __restrict__ W,
                          const float* __restrict__ bias,
                          float* __restrict__ out,
                          int nchunks)
{
    __shared__ unsigned short A_lds[ROWS * ASTRIDE];   // 29184 B
    __shared__ float          C_lds[VPC * 128];        // 8192 B

    const int tid  = threadIdx.x;
    const int lane = tid & 63;
    const int w    = tid >> 6;       // wave id 0..3 -> 16-wide O-tile
    const int ncol = lane & 15;
    const int kgrp = lane >> 4;
    const int G    = gridDim.x;

    // ---- persistent B fragments: W (fp32) -> bf16, register-resident ----
    short8 bfrag[KSTEPS];
    {
        const int o = w * 16 + ncol;
#pragma unroll
        for (int s = 0; s < KSTEPS; ++s) {
            const int kb = s * 32 + kgrp * 8;
            const float4* wp = (const float4*)(W + o * KDIM + kb);
            float4 w0 = wp[0];
            float4 w1 = wp[1];
            union { short8 v; unsigned int u[4]; } pk;
            pk.u[0] = pack_bf16(w0.x, w0.y);
            pk.u[1] = pack_bf16(w0.z, w0.w);
            pk.u[2] = pack_bf16(w1.x, w1.y);
            pk.u[3] = pack_bf16(w1.z, w1.w);
            bfrag[s] = pk.v;
        }
    }
    const float biasv = bias[w * 16 + ncol];

    // ---- staging plan: 224 segments ordered (lv, k, bb) so the (bb=0,bb=1)
    //      pair of one (vertex,k) occupies 16 CONSECUTIVE lanes -> each pair
    //      is a single contiguous 256B gather burst. ----
    const int l8 = tid & 7;
    int nidx[7];      // lv*7 + k      (neigh offset within chunk)
    int lbyte[7];     // byte addr in A_lds (row = 2lv+bb, col = k)
    int soff[7];      // short offset within a vertex's 128-short row: bb*64 + l8*8
#pragma unroll
    for (int i = 0; i < 7; ++i) {
        const int seg = (tid >> 3) + 32 * i;
        const int lv  = seg / 14;
        const int rem = seg - lv * 14;
        const int k   = rem >> 1;
        const int bb  = rem & 1;
        nidx[i]  = lv * KN + k;
        lbyte[i] = (2 * lv + bb) * (ASTRIDE * 2) + k * 128 + l8 * 16;
        soff[i]  = bb * 64 + l8 * 8;
    }

    const int ch0 = blockIdx.x;
    int    I[7];      // neigh indices for next chunk's gather
    short8 R[7];      // gathered data for current chunk

    // ---- prologue: fill the pipeline for ch0 ----
#pragma unroll
    for (int i = 0; i < 7; ++i) {
        int gi = ch0 * (VPC * KN) + nidx[i];
        I[i] = __builtin_nontemporal_load(&neigh[gi < NKMAX ? gi : 0]);
    }
#pragma unroll
    for (int i = 0; i < 7; ++i)
        R[i] = *(const short8*)(xt + (size_t)I[i] * 128 + soff[i]);
#pragma unroll
    for (int i = 0; i < 7; ++i) {
        int gi = (ch0 + G) * (VPC * KN) + nidx[i];
        I[i] = __builtin_nontemporal_load(&neigh[gi < NKMAX ? gi : 0]);
    }

    for (int ch = ch0; ch < nchunks; ch += G) {
        const int vb = ch * VPC;

        bar_lgkm();   // prev iter's A_lds reads + C_lds reads done

        // ---- commit current chunk's data to LDS; refill pipeline ----
#pragma unroll
        for (int i = 0; i < 7; ++i)
            *(short8*)((char*)A_lds + lbyte[i]) = R[i];
#pragma unroll
        for (int i = 0; i < 7; ++i)                       // data for ch+G
            R[i] = *(const short8*)(xt + (size_t)I[i] * 128 + soff[i]);
#pragma unroll
        for (int i = 0; i < 7; ++i) {                     // idx for ch+2G
            int gi = (ch + 2 * G) * (VPC * KN) + nidx[i];
            I[i] = __builtin_nontemporal_load(&neigh[gi < NKMAX ? gi : 0]);
        }

        bar_lgkm();   // A_lds populated

        // ---- compute: per wave, 32 rows x 16 out-cols ----
        f32x4 acc0 = {0.f, 0.f, 0.f, 0.f};
        f32x4 acc1 = {0.f, 0.f, 0.f, 0.f};
#pragma unroll
        for (int s = 0; s < KSTEPS; ++s) {
            const int kb = s * 32 + kgrp * 8;
            const short8 a0 = *(const short8*)&A_lds[ncol * ASTRIDE + kb];
            const short8 a1 = *(const short8*)&A_lds[(16 + ncol) * ASTRIDE + kb];
            acc0 = __builtin_amdgcn_mfma_f32_16x16x32_bf16(a0, bfrag[s], acc0, 0, 0, 0);
            acc1 = __builtin_amdgcn_mfma_f32_16x16x32_bf16(a1, bfrag[s], acc1, 0, 0, 0);
        }

        // ---- epilogue: C -> LDS in out-layout [lv][o][b] fp32 ----
        const int o2 = (w * 16 + ncol) * 2;
#pragma unroll
        for (int j = 0; j < 4; ++j) {
            const int r  = kgrp * 4 + j;
            C_lds[(r >> 1) * 128 + o2 + (r & 1)] = acc0[j] + biasv;
            const int r2 = 16 + r;
            C_lds[(r2 >> 1) * 128 + o2 + (r2 & 1)] = acc1[j] + biasv;
        }

        bar_lgkm();   // C_lds populated

        // ---- coalesced NON-TEMPORAL store: 4KB contiguous per instruction
        //      across the block (the ONLY store shape measured clean). ----
        f32x4* dst = (f32x4*)(out + vb * 128);
#pragma unroll
        for (int it = 0; it < 2; ++it) {
            const int fidx = tid + 256 * it;
            if (vb + (fidx >> 5) < NV)
                __builtin_nontemporal_store(((const f32x4*)C_lds)[fidx], &dst[fidx]);
        }
    }
}

// ---- fallback (ws too small): fp32-gather kernel ----
__global__ __launch_bounds__(256, 4)
void onering_mfma_f32(const float* __restrict__ x,
                      const int* __restrict__ neigh,
                      const float* __restrict__ W,
                      const float* __restrict__ bias,
                      float* __restrict__ out,
                      int nchunks)
{
    __shared__ unsigned short A_lds[ROWS * ASTRIDE];
    const int tid  = threadIdx.x;
    const int lane = tid & 63;
    const int w    = tid >> 6;
    const int ncol = lane & 15;
    const int kgrp = lane >> 4;

    short8 bfrag[KSTEPS];
    {
        const int o = w * 16 + ncol;
#pragma unroll
        for (int s = 0; s < KSTEPS; ++s) {
            const int kb = s * 32 + kgrp * 8;
            const float4* wp = (const float4*)(W + o * KDIM + kb);
            float4 w0 = wp[0];
            float4 w1 = wp[1];
            union { short8 v; unsigned int u[4]; } pk;
            pk.u[0] = pack_bf16(w0.x, w0.y);
            pk.u[1] = pack_bf16(w0.z, w0.w);
            pk.u[2] = pack_bf16(w1.x, w1.y);
            pk.u[3] = pack_bf16(w1.z, w1.w);
            bfrag[s] = pk.v;
        }
    }
    const float biasv = bias[w * 16 + ncol];
    const int off4  = tid & 31;
    const int sbase = tid >> 5;

    for (int ch = blockIdx.x; ch < nchunks; ch += gridDim.x) {
        const int vb = ch * VPC;
        __syncthreads();
#pragma unroll
        for (int i = 0; i < 14; ++i) {
            const int s  = sbase + 8 * i;
            const int lv = s / 7;
            const int k  = s - lv * 7;
            const int n  = vb + lv;
            int vi = 0;
            if (n < NV) vi = neigh[n * KN + k];
            const float4 g = ((const float4*)x)[vi * 32 + off4];
            const int base = k * 64 + 2 * off4;
            ((unsigned int*)A_lds)[((lv * 2)     * ASTRIDE + base) >> 1] = pack_bf16(g.x, g.z);
            ((unsigned int*)A_lds)[((lv * 2 + 1) * ASTRIDE + base) >> 1] = pack_bf16(g.y, g.w);
        }
        __syncthreads();
        f32x4 acc0 = {0.f, 0.f, 0.f, 0.f};
        f32x4 acc1 = {0.f, 0.f, 0.f, 0.f};
#pragma unroll
        for (int s = 0; s < KSTEPS; ++s) {
            const int kb = s * 32 + kgrp * 8;
            const short8 a0 = *(const short8*)&A_lds[ncol * ASTRIDE + kb];
            const short8 a1 = *(const short8*)&A_lds[(16 + ncol) * ASTRIDE + kb];
            acc0 = __builtin_amdgcn_mfma_f32_16x16x32_bf16(a0, bfrag[s], acc0, 0, 0, 0);
            acc1 = __builtin_amdgcn_mfma_f32_16x16x32_bf16(a1, bfrag[s], acc1, 0, 0, 0);
        }
        const int o = w * 16 + ncol;
#pragma unroll
        for (int j = 0; j < 4; ++j) {
            const int r = kgrp * 4 + j;
            {
                const int lv = r >> 1, bb = r & 1, n = vb + lv;
                if (n < NV) out[n * 128 + o * 2 + bb] = acc0[j] + biasv;
            }
            {
                const int m = 16 + r;
                const int lv = m >> 1, bb = m & 1, n = vb + lv;
                if (n < NV) out[n * 128 + o * 2 + bb] = acc1[j] + biasv;
            }
        }
    }
}

extern "C" void kernel_launch(void* const* d_in, const int* in_sizes, int n_in,
                              void* d_out, int out_size, void* d_ws, size_t ws_size,
                              hipStream_t stream) {
    const float* x     = (const float*)d_in[0];
    const int*   neigh = (const int*)d_in[1];   // int64 in ref -> int32 from harness
    const float* W     = (const float*)d_in[2];
    const float* bias  = (const float*)d_in[3];
    float*       out   = (float*)d_out;

    const int nchunks = (NV + VPC - 1) / VPC;   // 10241
    const size_t need = (size_t)NV * 128 * sizeof(unsigned short);  // 41.9 MB

    if (ws_size >= need) {
        unsigned short* xt = (unsigned short*)d_ws;
        const int nf4 = NV * 32;
        xcast<<<dim3((nf4 + 255) / 256), dim3(256), 0, stream>>>(x, (unsigned int*)xt, nf4);
        // 1024 = 4 blocks/CU exactly (LDS 37.4KB x4 = 149.5KB fits): persistent
        // grid, flat occupancy, prologue amortized over ~10 chunks.
        onering_mfma_bf16_v4<<<dim3(1024), dim3(256), 0, stream>>>(xt, neigh, W, bias, out, nchunks);
    } else {
        onering_mfma_f32<<<dim3(2560), dim3(256), 0, stream>>>(x, neigh, W, bias, out, nchunks);
    }
}

// Round 4
// 204.152 us; speedup vs baseline: 1.2621x; 1.0271x over previous
//
#include <hip/hip_runtime.h>

// Problem constants (from reference)
#define NV      163842      // vertices
#define CIN     64
#define KN      7
#define NKMAX   (NV * KN)   // 1,146,894 valid neigh entries
#define KDIM    448         // 7*64
#define KSTEPS  14          // 448 / 32
#define VPC     16          // vertices per chunk
#define ROWS    32          // M-rows per chunk (VPC * 2 batches)
#define NSEG    224         // segments per chunk (ROWS * 7)
#define ABUFS   (NSEG * 64) // shorts per A buffer (14336; 28672 B), linear [seg][128B]
#define ASTRIDE 456         // (fallback kernel only)

typedef short  short8 __attribute__((ext_vector_type(8)));
typedef float  f32x4  __attribute__((ext_vector_type(4)));

static __device__ __forceinline__ unsigned int pack_bf16(float a, float b) {
#if __has_builtin(__builtin_amdgcn_cvt_pk_bf16_f32)
    typedef __bf16 bf16x2 __attribute__((ext_vector_type(2)));
    union { bf16x2 v; unsigned int u; } cv;
    cv.v = __builtin_amdgcn_cvt_pk_bf16_f32(a, b);
    return cv.u;
#else
    unsigned int ua = __float_as_uint(a);
    unsigned int ub = __float_as_uint(b);
    ua = (ua + 0x7FFFu + ((ua >> 16) & 1u)) >> 16;
    ub = (ub + 0x7FFFu + ((ub >> 16) & 1u)) & 0xFFFF0000u;
    return ua | ub;
#endif
}

// LDS-only barrier: drains lgkmcnt but leaves the vmcnt queue alive.
static __device__ __forceinline__ void bar_lgkm() {
    asm volatile("s_waitcnt lgkmcnt(0)\n\ts_barrier" ::: "memory");
}

#define WAITVM(N) asm volatile("s_waitcnt vmcnt(" #N ")" ::: "memory")

// async 16B global->LDS DMA (per-lane global src; LDS dest is wave-linear)
static __device__ __forceinline__ void dma16(const unsigned short* g, unsigned short* l) {
    __builtin_amdgcn_global_load_lds(
        (const __attribute__((address_space(1))) unsigned int*)g,
        (__attribute__((address_space(3))) unsigned int*)l, 16, 0, 0);
}

// ---- pre-pass: x [N][C][B] fp32 -> xt [N][B][C] bf16 (256B per vertex) ----
__global__ __launch_bounds__(256)
void xcast(const float* __restrict__ x, unsigned int* __restrict__ xt, int nf4)
{
    const int f = blockIdx.x * 256 + threadIdx.x;   // float4 index over x
    if (f >= nf4) return;                           // nf4 = NV*32
    const f32x4 g = __builtin_nontemporal_load(&((const f32x4*)x)[f]);
    const int v = f >> 5;
    const int r = f & 31;                           // u32 slot; c0 = 2r
    xt[v * 64 + r]      = pack_bf16(g[0], g[2]);    // batch 0: c0, c0+1
    xt[v * 64 + 32 + r] = pack_bf16(g[1], g[3]);    // batch 1
}

// ---- main v5: global_load_lds DMA staging, double-buffered linear A_lds with
//      XOR piece-swizzle (inverse-swizzled global src, swizzled ds_read),
//      counted vmcnt (never 0 in-loop), ONE barrier per chunk. ----
__global__ __launch_bounds__(256, 2)
void onering_mfma_bf16_v5(const unsigned short* __restrict__ xt,
                          const int* __restrict__ neigh,
                          const float* __restrict__ W,
                          const float* __restrict__ bias,
                          float* __restrict__ out,
                          int nchunks)
{
    // A: [2][224 segs][64 shorts] linear (DMA-writable); seg = lv*14 + k*2 + bb.
    // piece p (16B) of seg stored at slot p ^ (seg&7)  [involution].
    __shared__ __align__(16) unsigned short A_lds[2 * ABUFS];  // 57344 B
    __shared__ __align__(16) float          C_lds[VPC * 128];  // 8192 B

    const int tid  = threadIdx.x;
    const int lane = tid & 63;
    const int w    = tid >> 6;       // wave id 0..3 -> 16-wide O-tile
    const int ncol = lane & 15;
    const int kgrp = lane >> 4;
    const int G    = gridDim.x;

    // ---- persistent B fragments: W (fp32) -> bf16, register-resident ----
    short8 bfrag[KSTEPS];
    {
        const int o = w * 16 + ncol;
#pragma unroll
        for (int s = 0; s < KSTEPS; ++s) {
            const int kb = s * 32 + kgrp * 8;
            const float4* wp = (const float4*)(W + o * KDIM + kb);
            float4 w0 = wp[0];
            float4 w1 = wp[1];
            union { short8 v; unsigned int u[4]; } pk;
            pk.u[0] = pack_bf16(w0.x, w0.y);
            pk.u[1] = pack_bf16(w0.z, w0.w);
            pk.u[2] = pack_bf16(w1.x, w1.y);
            pk.u[3] = pack_bf16(w1.z, w1.w);
            bfrag[s] = pk.v;
        }
    }
    const float biasv = bias[w * 16 + ncol];

    // ---- staging plan: 224 segs, 8 lanes x 16B each; LDS dest is LINEAR
    //      (wave base + lane*16); global src piece = l8 ^ (seg&7). ----
    const int l8 = tid & 7;
    int nidx[7];      // lv*7 + k  (neigh offset within chunk)
    int ldst[7];      // LDS short offset within one A buffer (linear)
    int gso[7];       // short offset within vertex: bb*64 + (l8^(seg&7))*8
#pragma unroll
    for (int i = 0; i < 7; ++i) {
        const int seg = (tid >> 3) + 32 * i;
        const int lv  = seg / 14;
        const int rem = seg - lv * 14;
        const int k   = rem >> 1;
        const int bb  = rem & 1;
        nidx[i] = lv * KN + k;
        ldst[i] = seg * 64 + l8 * 8;                 // linear: base + lane*16B
        gso[i]  = bb * 64 + ((l8 ^ (seg & 7)) << 3); // inverse-swizzled source
    }

    const int ch0 = blockIdx.x;
    int I[7];    // indices for chunk ch+G (DMA operands this iter)
    int I2[7];   // indices for chunk ch+2G (in flight)

    // ---- prologue ----
#pragma unroll
    for (int i = 0; i < 7; ++i) {
        int gi = ch0 * (VPC * KN) + nidx[i];
        I[i] = __builtin_nontemporal_load(&neigh[gi < NKMAX ? gi : 0]);
    }
    WAITVM(0);
#pragma unroll
    for (int i = 0; i < 7; ++i)                       // DMA ch0 -> buf0
        dma16(xt + (size_t)I[i] * 128 + gso[i], A_lds + ldst[i]);
#pragma unroll
    for (int i = 0; i < 7; ++i) {                     // idx ch0+G
        int gi = (ch0 + G) * (VPC * KN) + nidx[i];
        I2[i] = __builtin_nontemporal_load(&neigh[gi < NKMAX ? gi : 0]);
    }
    WAITVM(0);                                        // one-time full drain
#pragma unroll
    for (int i = 0; i < 7; ++i) I[i] = I2[i];
#pragma unroll
    for (int i = 0; i < 7; ++i) {                     // idx ch0+2G -> I2
        int gi = (ch0 + 2 * G) * (VPC * KN) + nidx[i];
        I2[i] = __builtin_nontemporal_load(&neigh[gi < NKMAX ? gi : 0]);
    }
    // invariant entering loop: buf0 = ch0 resident; I = idx(ch+G); I2 in flight.

    int cur = 0;
    for (int ch = ch0; ch < nchunks; ch += G) {
        const int vb = ch * VPC;

        // 1. issue DMA for ch+G into back buffer (outstanding: IDX(7) + these 7 [+ DMA_ch(7) steady])
        unsigned short* Aw = A_lds + (cur ^ 1) * ABUFS;
#pragma unroll
        for (int i = 0; i < 7; ++i)
            dma16(xt + (size_t)I[i] * 128 + gso[i], Aw + ldst[i]);

        // 2. drain DMA_ch (oldest 7 of 21): counted wait, pipeline stays alive
        WAITVM(14);
        __builtin_amdgcn_s_barrier();   // all waves' ch-data in cur

        // 3. rotate idx regs (drains IDX, keeps DMA_{ch+G})
        WAITVM(7);
#pragma unroll
        for (int i = 0; i < 7; ++i) I[i] = I2[i];
        // 4. prefetch idx for ch+3G
#pragma unroll
        for (int i = 0; i < 7; ++i) {
            int gi = (ch + 3 * G) * (VPC * KN) + nidx[i];
            I2[i] = __builtin_nontemporal_load(&neigh[gi < NKMAX ? gi : 0]);
        }

        // 5. compute from front buffer (swizzled ds_read_b128, conflict-free)
        const unsigned short* Ab = A_lds + cur * ABUFS;
        const int rb0 = (ncol >> 1) * 14 + (ncol & 1);   // seg base for row ncol
        f32x4 acc0 = {0.f, 0.f, 0.f, 0.f};
        f32x4 acc1 = {0.f, 0.f, 0.f, 0.f};
#pragma unroll
        for (int s = 0; s < KSTEPS; ++s) {
            const int p0   = (s & 1) * 4 + kgrp;
            const int seg0 = rb0 + (s >> 1) * 2;         // row ncol
            const int slot = (p0 ^ (seg0 & 7)) << 3;     // (seg0+112)&7 == seg0&7
            const short8 a0 = *(const short8*)&Ab[seg0 * 64 + slot];
            const short8 a1 = *(const short8*)&Ab[(seg0 + 112) * 64 + slot]; // row 16+ncol
            acc0 = __builtin_amdgcn_mfma_f32_16x16x32_bf16(a0, bfrag[s], acc0, 0, 0, 0);
            acc1 = __builtin_amdgcn_mfma_f32_16x16x32_bf16(a1, bfrag[s], acc1, 0, 0, 0);
        }

        // 6. epilogue: C -> LDS in out-layout, then clean 4KB-contig nt stores
        const int o2 = (w * 16 + ncol) * 2;
#pragma unroll
        for (int j = 0; j < 4; ++j) {
            const int r  = kgrp * 4 + j;
            C_lds[(r >> 1) * 128 + o2 + (r & 1)] = acc0[j] + biasv;
            const int r2 = 16 + r;
            C_lds[(r2 >> 1) * 128 + o2 + (r2 & 1)] = acc1[j] + biasv;
        }
        bar_lgkm();   // C_lds populated (also drains this iter's A ds_reads)
        f32x4* dst = (f32x4*)(out + vb * 128);
#pragma unroll
        for (int it = 0; it < 2; ++it) {
            const int fidx = tid + 256 * it;
            if (vb + (fidx >> 5) < NV)
                __builtin_nontemporal_store(((const f32x4*)C_lds)[fidx], &dst[fidx]);
        }

        cur ^= 1;
    }
}

// ---- fallback (ws too small): fp32-gather kernel (unchanged) ----
__global__ __launch_bounds__(256, 4)
void onering_mfma_f32(const float* __restrict__ x,
                      const int* __restrict__ neigh,
                      const float* __restrict__ W,
                      const float* __restrict__ bias,
                      float* __restrict__ out,
                      int nchunks)
{
    __shared__ unsigned short A_lds[ROWS * ASTRIDE];
    const int tid  = threadIdx.x;
    const int lane = tid & 63;
    const int w    = tid >> 6;
    const int ncol = lane & 15;
    const int kgrp = lane >> 4;

    short8 bfrag[KSTEPS];
    {
        const int o = w * 16 + ncol;
#pragma unroll
        for (int s = 0; s < KSTEPS; ++s) {
            const int kb = s * 32 + kgrp * 8;
            const float4* wp = (const float4*)(W + o * KDIM + kb);
            float4 w0 = wp[0];
            float4 w1 = wp[1];
            union { short8 v; unsigned int u[4]; } pk;
            pk.u[0] = pack_bf16(w0.x, w0.y);
            pk.u[1] = pack_bf16(w0.z, w0.w);
            pk.u[2] = pack_bf16(w1.x, w1.y);
            pk.u[3] = pack_bf16(w1.z, w1.w);
            bfrag[s] = pk.v;
        }
    }
    const float biasv = bias[w * 16 + ncol];
    const int off4  = tid & 31;
    const int sbase = tid >> 5;

    for (int ch = blockIdx.x; ch < nchunks; ch += gridDim.x) {
        const int vb = ch * VPC;
        __syncthreads();
#pragma unroll
        for (int i = 0; i < 14; ++i) {
            const int s  = sbase + 8 * i;
            const int lv = s / 7;
            const int k  = s - lv * 7;
            const int n  = vb + lv;
            int vi = 0;
            if (n < NV) vi = neigh[n * KN + k];
            const float4 g = ((const float4*)x)[vi * 32 + off4];
            const int base = k * 64 + 2 * off4;
            ((unsigned int*)A_lds)[((lv * 2)     * ASTRIDE + base) >> 1] = pack_bf16(g.x, g.z);
            ((unsigned int*)A_lds)[((lv * 2 + 1) * ASTRIDE + base) >> 1] = pack_bf16(g.y, g.w);
        }
        __syncthreads();
        f32x4 acc0 = {0.f, 0.f, 0.f, 0.f};
        f32x4 acc1 = {0.f, 0.f, 0.f, 0.f};
#pragma unroll
        for (int s = 0; s < KSTEPS; ++s) {
            const int kb = s * 32 + kgrp * 8;
            const short8 a0 = *(const short8*)&A_lds[ncol * ASTRIDE + kb];
            const short8 a1 = *(const short8*)&A_lds[(16 + ncol) * ASTRIDE + kb];
            acc0 = __builtin_amdgcn_mfma_f32_16x16x32_bf16(a0, bfrag[s], acc0, 0, 0, 0);
            acc1 = __builtin_amdgcn_mfma_f32_16x16x32_bf16(a1, bfrag[s], acc1, 0, 0, 0);
        }
        const int o = w * 16 + ncol;
#pragma unroll
        for (int j = 0; j < 4; ++j) {
            const int r = kgrp * 4 + j;
            {
                const int lv = r >> 1, bb = r & 1, n = vb + lv;
                if (n < NV) out[n * 128 + o * 2 + bb] = acc0[j] + biasv;
            }
            {
                const int m = 16 + r;
                const int lv = m >> 1, bb = m & 1, n = vb + lv;
                if (n < NV) out[n * 128 + o * 2 + bb] = acc1[j] + biasv;
            }
        }
    }
}

extern "C" void kernel_launch(void* const* d_in, const int* in_sizes, int n_in,
                              void* d_out, int out_size, void* d_ws, size_t ws_size,
                              hipStream_t stream) {
    const float* x     = (const float*)d_in[0];
    const int*   neigh = (const int*)d_in[1];   // int64 in ref -> int32 from harness
    const float* W     = (const float*)d_in[2];
    const float* bias  = (const float*)d_in[3];
    float*       out   = (float*)d_out;

    const int nchunks = (NV + VPC - 1) / VPC;   // 10241
    const size_t need = (size_t)NV * 128 * sizeof(unsigned short);  // 41.9 MB

    if (ws_size >= need) {
        unsigned short* xt = (unsigned short*)d_ws;
        const int nf4 = NV * 32;
        xcast<<<dim3((nf4 + 255) / 256), dim3(256), 0, stream>>>(x, (unsigned int*)xt, nf4);
        // 512 = 2 blocks/CU (64KB LDS each); ~20 chunks per block persistent.
        onering_mfma_bf16_v5<<<dim3(512), dim3(256), 0, stream>>>(xt, neigh, W, bias, out, nchunks);
    } else {
        onering_mfma_f32<<<dim3(2560), dim3(256), 0, stream>>>(x, neigh, W, bias, out, nchunks);
    }
}

// Round 5
// 202.935 us; speedup vs baseline: 1.2697x; 1.0060x over previous
//
#include <hip/hip_runtime.h>

// Problem constants (from reference)
#define NV      163842      // vertices
#define CIN     64
#define KN      7
#define NKMAX   (NV * KN)   // 1,146,894 valid neigh entries
#define KDIM    448         // 7*64
#define VPC     16          // vertices per chunk
#define ROWS    32          // M-rows per chunk (VPC * 2 batches)
#define NSEG    224         // segments per chunk (ROWS * 7)
#define ABUFS   (NSEG * 64) // shorts per A buffer (14336; 28672 B), linear [seg][128B]
#define KSTEPS  14          // per-wave K-steps: 224 / 16 (K-split halves)
#define ASTRIDE 456         // (fallback kernel only)

typedef short  short8 __attribute__((ext_vector_type(8)));
typedef float  f32x4  __attribute__((ext_vector_type(4)));
typedef float  f32x16 __attribute__((ext_vector_type(16)));

static __device__ __forceinline__ unsigned int pack_bf16(float a, float b) {
#if __has_builtin(__builtin_amdgcn_cvt_pk_bf16_f32)
    typedef __bf16 bf16x2 __attribute__((ext_vector_type(2)));
    union { bf16x2 v; unsigned int u; } cv;
    cv.v = __builtin_amdgcn_cvt_pk_bf16_f32(a, b);
    return cv.u;
#else
    unsigned int ua = __float_as_uint(a);
    unsigned int ub = __float_as_uint(b);
    ua = (ua + 0x7FFFu + ((ua >> 16) & 1u)) >> 16;
    ub = (ub + 0x7FFFu + ((ub >> 16) & 1u)) & 0xFFFF0000u;
    return ua | ub;
#endif
}

// LDS-only barrier: drains lgkmcnt but leaves the vmcnt queue alive.
static __device__ __forceinline__ void bar_lgkm() {
    asm volatile("s_waitcnt lgkmcnt(0)\n\ts_barrier" ::: "memory");
}

#define WAITVM(N) asm volatile("s_waitcnt vmcnt(" #N ")" ::: "memory")

// async 16B global->LDS DMA (per-lane global src; LDS dest is wave-linear)
static __device__ __forceinline__ void dma16(const unsigned short* g, unsigned short* l) {
    __builtin_amdgcn_global_load_lds(
        (const __attribute__((address_space(1))) unsigned int*)g,
        (__attribute__((address_space(3))) unsigned int*)l, 16, 0, 0);
}

// ---- pre-pass: x [N][C][B] fp32 -> xt [N][B][C] bf16 (256B per vertex) ----
__global__ __launch_bounds__(256)
void xcast(const float* __restrict__ x, unsigned int* __restrict__ xt, int nf4)
{
    const int f = blockIdx.x * 256 + threadIdx.x;   // float4 index over x
    if (f >= nf4) return;                           // nf4 = NV*32
    const f32x4 g = __builtin_nontemporal_load(&((const f32x4*)x)[f]);
    const int v = f >> 5;
    const int r = f & 31;                           // u32 slot; c0 = 2r
    xt[v * 64 + r]      = pack_bf16(g[0], g[2]);    // batch 0: c0, c0+1
    xt[v * 64 + 32 + r] = pack_bf16(g[1], g[3]);    // batch 1
}

// ---- main v6: 32x32x16 MFMA with K-split to HALVE LDS fragment reads.
//      Wave (wc = col-half, kh = K-half): each A fragment covers all 32 M-rows,
//      so A ds_reads drop 112 -> 56 per chunk. kh=1 partials merged via P_lds.
//      DMA staging + swizzle + counted-vmcnt pipeline carried from v5. ----
__global__ __launch_bounds__(256, 2)
void onering_mfma_bf16_v6(const unsigned short* __restrict__ xt,
                          const int* __restrict__ neigh,
                          const float* __restrict__ W,
                          const float* __restrict__ bias,
                          float* __restrict__ out,
                          int nchunks)
{
    // A: [2][224 segs][64 shorts] linear (DMA-writable); seg = lv*14 + k*2 + bb.
    // 16B piece p of seg stored at slot p ^ (seg&7)  [involution].
    __shared__ __align__(16) unsigned short A_lds[2 * ABUFS];  // 57344 B
    __shared__ __align__(16) float          P_lds[2 * 1024];   // 8192 B partials
    __shared__ __align__(16) float          C_lds[VPC * 128];  // 8192 B out stage

    const int tid  = threadIdx.x;
    const int lane = tid & 63;
    const int w    = tid >> 6;       // wave 0..3
    const int wc   = w & 1;          // col half: o in [wc*32, wc*32+32)
    const int kh   = w >> 1;         // K half:  kdim in [kh*224, kh*224+224)
    const int col  = lane & 31;
    const int hi   = lane >> 5;
    const int G    = gridDim.x;

    // ---- persistent B fragments: 14 x 8 bf16 (56 VGPR).
    //      B[k = hi*8+j][n = col] = W[wc*32+col][kh*224 + s*16 + hi*8 + j]. ----
    short8 bfrag[KSTEPS];
    {
        const int o   = wc * 32 + col;
        const int kb0 = kh * 224 + hi * 8;
#pragma unroll
        for (int s = 0; s < KSTEPS; ++s) {
            const float4* wp = (const float4*)(W + o * KDIM + kb0 + s * 16);
            float4 w0 = wp[0];
            float4 w1 = wp[1];
            union { short8 v; unsigned int u[4]; } pk;
            pk.u[0] = pack_bf16(w0.x, w0.y);
            pk.u[1] = pack_bf16(w0.z, w0.w);
            pk.u[2] = pack_bf16(w1.x, w1.y);
            pk.u[3] = pack_bf16(w1.z, w1.w);
            bfrag[s] = pk.v;
        }
    }
    const float biasv = bias[wc * 32 + col];

    // ---- A-read addressing (loop-invariant): M-row r = col -> (lv, bb);
    //      lane reads 8 bf16 at kdim kk0 = kh*224 + s*16 + hi*8. ----
    const int rb  = (col >> 1) * 14 + (col & 1);   // seg base (lv*14 + bb)
    const int khb = kh * 224 + hi * 8;

    // ---- staging plan: 224 segs, 8 lanes x 16B each; LDS dest LINEAR,
    //      global src piece = l8 ^ (seg&7) (inverse swizzle). ----
    const int l8 = tid & 7;
    int nidx[7];      // lv*7 + k  (neigh offset within chunk)
    int ldst[7];      // LDS short offset within one A buffer (linear)
    int gso[7];       // short offset within vertex: bb*64 + (l8^(seg&7))*8
#pragma unroll
    for (int i = 0; i < 7; ++i) {
        const int seg = (tid >> 3) + 32 * i;
        const int lv  = seg / 14;
        const int rem = seg - lv * 14;
        const int k   = rem >> 1;
        const int bb  = rem & 1;
        nidx[i] = lv * KN + k;
        ldst[i] = seg * 64 + l8 * 8;
        gso[i]  = bb * 64 + ((l8 ^ (seg & 7)) << 3);
    }

    const int ch0 = blockIdx.x;
    int I[7];   // neigh indices for the chunk to stage at next loop top

    // ---- prologue: stage ch0 into buf0; leave queue EMPTY (matches loop) ----
#pragma unroll
    for (int i = 0; i < 7; ++i) {
        int gi = ch0 * (VPC * KN) + nidx[i];
        I[i] = __builtin_nontemporal_load(&neigh[gi < NKMAX ? gi : 0]);
    }
    WAITVM(0);
#pragma unroll
    for (int i = 0; i < 7; ++i)
        dma16(xt + (size_t)I[i] * 128 + gso[i], A_lds + ldst[i]);
#pragma unroll
    for (int i = 0; i < 7; ++i) {
        int gi = (ch0 + G) * (VPC * KN) + nidx[i];
        I[i] = __builtin_nontemporal_load(&neigh[gi < NKMAX ? gi : 0]);
    }
    WAITVM(0);   // full drain: ch0 resident, I = idx(ch0+G) valid

    int cur = 0;
    for (int ch = ch0; ch < nchunks; ch += G) {
        const int vb = ch * VPC;

        // 1. drain to 2 (prev stores): completes prev DMA (this chunk's data)
        //    and prev idx loads (I). Steady-state queue: 18 -> 2.
        WAITVM(2);

        // 2. issue DMA for ch+G into back buffer
        unsigned short* Aw = A_lds + (cur ^ 1) * ABUFS;
#pragma unroll
        for (int i = 0; i < 7; ++i)
            dma16(xt + (size_t)I[i] * 128 + gso[i], Aw + ldst[i]);

        // 3. all waves have their chunk-ch data drained -> publish
        __builtin_amdgcn_s_barrier();

        // 4. prefetch idx for ch+2G (needed at next loop top)
#pragma unroll
        for (int i = 0; i < 7; ++i) {
            int gi = (ch + 2 * G) * (VPC * KN) + nidx[i];
            I[i] = __builtin_nontemporal_load(&neigh[gi < NKMAX ? gi : 0]);
        }

        // 5. compute: one 32x32 tile per wave over its K-half (14 MFMA)
        const unsigned short* Ab = A_lds + cur * ABUFS;
        f32x16 acc = {0.f};
#pragma unroll
        for (int s = 0; s < KSTEPS; ++s) {
            const int kk0  = khb + s * 16;
            const int k    = kk0 >> 6;
            const int p    = (kk0 >> 3) & 7;
            const int seg  = rb + 2 * k;
            const int slot = (p ^ (seg & 7)) << 3;
            const short8 a = *(const short8*)&Ab[seg * 64 + slot];
            acc = __builtin_amdgcn_mfma_f32_32x32x16_bf16(a, bfrag[s], acc, 0, 0, 0);
        }

        // 6. K-half merge: kh=1 waves post partials; kh=0 waves add+bias -> C_lds.
        //    C layout (m74): col = lane&31, row = (g&3) + 8*(g>>2) + 4*hi.
        if (kh) {
#pragma unroll
            for (int g = 0; g < 16; ++g) {
                const int row = (g & 3) + 8 * (g >> 2) + 4 * hi;
                P_lds[wc * 1024 + row * 32 + col] = acc[g];
            }
        }
        bar_lgkm();   // partials visible (also drains this iter's A ds_reads)
        if (!kh) {
#pragma unroll
            for (int g = 0; g < 16; ++g) {
                const int row = (g & 3) + 8 * (g >> 2) + 4 * hi;
                const float v = acc[g] + P_lds[wc * 1024 + row * 32 + col] + biasv;
                // out-layout: [lv][o][batch]; row = 2*lv + batch
                C_lds[(row >> 1) * 128 + (wc * 32 + col) * 2 + (row & 1)] = v;
            }
        }
        bar_lgkm();   // C_lds populated

        // 7. block-wide clean nt stores: 4KB contiguous per instruction pair
        f32x4* dst = (f32x4*)(out + vb * 128);
#pragma unroll
        for (int it = 0; it < 2; ++it) {
            const int fidx = tid + 256 * it;
            if (vb + (fidx >> 5) < NV)
                __builtin_nontemporal_store(((const f32x4*)C_lds)[fidx], &dst[fidx]);
        }

        cur ^= 1;
    }
}

// ---- fallback (ws too small): fp32-gather kernel (unchanged) ----
__global__ __launch_bounds__(256, 4)
void onering_mfma_f32(const float* __restrict__ x,
                      const int* __restrict__ neigh,
                      const float* __restrict__ W,
                      const float* __restrict__ bias,
                      float* __restrict__ out,
                      int nchunks)
{
    typedef float f32x4l __attribute__((ext_vector_type(4)));
    __shared__ unsigned short A_lds[ROWS * ASTRIDE];
    const int tid  = threadIdx.x;
    const int lane = tid & 63;
    const int w    = tid >> 6;
    const int ncol = lane & 15;
    const int kgrp = lane >> 4;

    short8 bfrag[14];
    {
        const int o = w * 16 + ncol;
#pragma unroll
        for (int s = 0; s < 14; ++s) {
            const int kb = s * 32 + kgrp * 8;
            const float4* wp = (const float4*)(W + o * KDIM + kb);
            float4 w0 = wp[0];
            float4 w1 = wp[1];
            union { short8 v; unsigned int u[4]; } pk;
            pk.u[0] = pack_bf16(w0.x, w0.y);
            pk.u[1] = pack_bf16(w0.z, w0.w);
            pk.u[2] = pack_bf16(w1.x, w1.y);
            pk.u[3] = pack_bf16(w1.z, w1.w);
            bfrag[s] = pk.v;
        }
    }
    const float biasv = bias[w * 16 + ncol];
    const int off4  = tid & 31;
    const int sbase = tid >> 5;

    for (int ch = blockIdx.x; ch < nchunks; ch += gridDim.x) {
        const int vb = ch * VPC;
        __syncthreads();
#pragma unroll
        for (int i = 0; i < 14; ++i) {
            const int s  = sbase + 8 * i;
            const int lv = s / 7;
            const int k  = s - lv * 7;
            const int n  = vb + lv;
            int vi = 0;
            if (n < NV) vi = neigh[n * KN + k];
            const float4 g = ((const float4*)x)[vi * 32 + off4];
            const int base = k * 64 + 2 * off4;
            ((unsigned int*)A_lds)[((lv * 2)     * ASTRIDE + base) >> 1] = pack_bf16(g.x, g.z);
            ((unsigned int*)A_lds)[((lv * 2 + 1) * ASTRIDE + base) >> 1] = pack_bf16(g.y, g.w);
        }
        __syncthreads();
        f32x4l acc0 = {0.f, 0.f, 0.f, 0.f};
        f32x4l acc1 = {0.f, 0.f, 0.f, 0.f};
#pragma unroll
        for (int s = 0; s < 14; ++s) {
            const int kb = s * 32 + kgrp * 8;
            const short8 a0 = *(const short8*)&A_lds[ncol * ASTRIDE + kb];
            const short8 a1 = *(const short8*)&A_lds[(16 + ncol) * ASTRIDE + kb];
            acc0 = __builtin_amdgcn_mfma_f32_16x16x32_bf16(a0, bfrag[s], acc0, 0, 0, 0);
            acc1 = __builtin_amdgcn_mfma_f32_16x16x32_bf16(a1, bfrag[s], acc1, 0, 0, 0);
        }
        const int o = w * 16 + ncol;
#pragma unroll
        for (int j = 0; j < 4; ++j) {
            const int r = kgrp * 4 + j;
            {
                const int lv = r >> 1, bb = r & 1, n = vb + lv;
                if (n < NV) out[n * 128 + o * 2 + bb] = acc0[j] + biasv;
            }
            {
                const int m = 16 + r;
                const int lv = m >> 1, bb = m & 1, n = vb + lv;
                if (n < NV) out[n * 128 + o * 2 + bb] = acc1[j] + biasv;
            }
        }
    }
}

extern "C" void kernel_launch(void* const* d_in, const int* in_sizes, int n_in,
                              void* d_out, int out_size, void* d_ws, size_t ws_size,
                              hipStream_t stream) {
    const float* x     = (const float*)d_in[0];
    const int*   neigh = (const int*)d_in[1];   // int64 in ref -> int32 from harness
    const float* W     = (const float*)d_in[2];
    const float* bias  = (const float*)d_in[3];
    float*       out   = (float*)d_out;

    const int nchunks = (NV + VPC - 1) / VPC;   // 10241
    const size_t need = (size_t)NV * 128 * sizeof(unsigned short);  // 41.9 MB

    if (ws_size >= need) {
        unsigned short* xt = (unsigned short*)d_ws;
        const int nf4 = NV * 32;
        xcast<<<dim3((nf4 + 255) / 256), dim3(256), 0, stream>>>(x, (unsigned int*)xt, nf4);
        // 512 = 2 blocks/CU (73.7KB LDS each, 147.5KB/CU); ~20 chunks per block.
        onering_mfma_bf16_v6<<<dim3(512), dim3(256), 0, stream>>>(xt, neigh, W, bias, out, nchunks);
    } else {
        onering_mfma_f32<<<dim3(2560), dim3(256), 0, stream>>>(x, neigh, W, bias, out, nchunks);
    }
}